// Round 17
// baseline (314.077 us; speedup 1.0000x reference)
//
#include <hip/hip_runtime.h>
#include <cmath>

#define N_NODES 100000
#define N_EDGES 1600000
#define IN_DIM 128
#define HID 96
#define NCLS 16
#define NB_GATH 2560  // gather grid (fixed, for stats partials)

// bucket-sort CSR build (contention-free)
#define BSHIFT 7
#define BNODES 128
#define NBUK 782
#define TILE_E 8192
#define NBLK_E 196
#define NBLK_Q 24
#define NBLK_R 4

#define KPAD1 (IN_DIM + 8)   // 136
#define KPAD2 (HID + 8)      // 104

typedef unsigned int uint;
typedef unsigned short ushort;
typedef __attribute__((ext_vector_type(8))) short short8v;
typedef __attribute__((ext_vector_type(4))) float float4v;

__device__ __forceinline__ ushort f2bf(float x) {  // RNE f32->bf16
    uint b = __float_as_uint(x);
    uint r = (b + 0x7FFFu + ((b >> 16) & 1u)) >> 16;
    return (ushort)r;
}
__device__ __forceinline__ float bf2f(ushort u) {
    return __uint_as_float(((uint)u) << 16);
}
__device__ __forceinline__ float bf_lo(uint w) { return __uint_as_float(w << 16); }
__device__ __forceinline__ float bf_hi(uint w) { return __uint_as_float(w & 0xFFFF0000u); }
__device__ __forceinline__ uint pack2bf(float a, float b) {
    return (uint)f2bf(a) | ((uint)f2bf(b) << 16);
}

// XCD-swizzled tile mapping (bijective for NBLK_E = 8*NBLK_Q + NBLK_R).
__device__ __forceinline__ int tile_of(int blk) {
    int xcd = blk & 7, slot = blk >> 3;
    return (xcd < NBLK_R) ? xcd * (NBLK_Q + 1) + slot
                          : NBLK_R * (NBLK_Q + 1) + (xcd - NBLK_R) * NBLK_Q + slot;
}

// ---------------------------------------------------------------------------
// wfuse: W_t1[n][k] = bf16((W_emb @ W1)[k][n]); bf = b_emb @ W1;
// also W_t2[n][k] = bf16(W2[k][n]). All weight prep in ONE dispatch.
// ---------------------------------------------------------------------------
__global__ __launch_bounds__(256) void wfuse(const float* __restrict__ W_emb,
                                             const float* __restrict__ W1,
                                             const float* __restrict__ b_emb,
                                             const float* __restrict__ W2,
                                             ushort* __restrict__ W_t1,
                                             ushort* __restrict__ W_t2,
                                             float* __restrict__ bf) {
    __shared__ float W1s[HID * HID];
    for (int i = threadIdx.x; i < HID * HID / 4; i += 256)
        ((float4*)W1s)[i] = ((const float4*)W1)[i];
    __syncthreads();
    int idx = blockIdx.x * 256 + threadIdx.x;
    if (idx < IN_DIM * HID) {
        int i = idx / HID, j = idx - (idx / HID) * HID;
        float acc = 0.f;
        for (int k = 0; k < HID; ++k)
            acc = fmaf(W_emb[(size_t)i * HID + k], W1s[k * HID + j], acc);
        W_t1[(size_t)j * KPAD1 + i] = f2bf(acc);
    }
    if (idx < HID * HID) {
        int k = idx / HID, n = idx - (idx / HID) * HID;
        W_t2[(size_t)n * KPAD2 + k] = f2bf(W2[idx]);
    }
    if (idx < HID) {
        float acc = 0.f;
        for (int k = 0; k < HID; ++k)
            acc = fmaf(b_emb[k], W1s[k * HID + idx], acc);
        bf[idx] = acc;
    }
}

// ---------------------------------------------------------------------------
// MFMA layer-1 GEMM: T1 = bf16(X) @ Wf + bf -> bf16 table.
// ---------------------------------------------------------------------------
__global__ __launch_bounds__(384) void gemm_l1(const float* __restrict__ X,
                                               const ushort* __restrict__ W_tg,
                                               const float* __restrict__ bias,
                                               ushort* __restrict__ outB) {
    constexpr int K = IN_DIM, KPAD = KPAD1;
    __shared__ ushort A_s[96 * KPAD];
    __shared__ ushort W_t[96 * KPAD];
    __shared__ float bs[HID];
    if (threadIdx.x < HID) bs[threadIdx.x] = bias[threadIdx.x];

    const int rbase = blockIdx.x * 96;
    for (int c = threadIdx.x; c < 96 * (K / 8); c += 384) {
        int row = c / (K / 8), ko = (c - row * (K / 8)) * 8;
        int gr = min(rbase + row, N_NODES - 1);
        const float* xp = X + (size_t)gr * K + ko;
        float4 v0 = *(const float4*)xp;
        float4 v1 = *(const float4*)(xp + 4);
        uint4 p;
        p.x = pack2bf(v0.x, v0.y);
        p.y = pack2bf(v0.z, v0.w);
        p.z = pack2bf(v1.x, v1.y);
        p.w = pack2bf(v1.z, v1.w);
        *(uint4*)&A_s[row * KPAD + ko] = p;
    }
    for (int i = threadIdx.x; i < 96 * KPAD / 8; i += 384)
        ((uint4*)W_t)[i] = ((const uint4*)W_tg)[i];
    __syncthreads();

    const int lane = threadIdx.x & 63, w = threadIdx.x >> 6;
    const int ar = lane & 15, kg = lane >> 4;
    float4v acc[6] = {};
    const ushort* ap = &A_s[(w * 16 + ar) * KPAD + kg * 8];
    const ushort* bp = &W_t[ar * KPAD + kg * 8];
#pragma unroll
    for (int kc = 0; kc < K / 32; ++kc) {
        short8v af = *(const short8v*)(ap + kc * 32);
#pragma unroll
        for (int ct = 0; ct < 6; ++ct) {
            short8v bfv = *(const short8v*)(bp + ct * 16 * KPAD + kc * 32);
            acc[ct] = __builtin_amdgcn_mfma_f32_16x16x32_bf16(af, bfv, acc[ct], 0, 0, 0);
        }
    }
#pragma unroll
    for (int ct = 0; ct < 6; ++ct) {
        int col = ct * 16 + ar;
        float bb = bs[col];
#pragma unroll
        for (int i = 0; i < 4; ++i) {
            int grow = rbase + w * 16 + kg * 4 + i;
            if (grow < N_NODES)
                outB[(size_t)grow * HID + col] = f2bf(acc[ct][i] + bb);
        }
    }
}

// ---------------------------------------------------------------------------
// MFMA layer-2 GEMM: T2 = relu(bn1(z1)) @ W2 -> bf16 (BN+ReLU at A-staging).
// ---------------------------------------------------------------------------
__global__ __launch_bounds__(384) void gemm_l2(const ushort* __restrict__ X,
                                               const ushort* __restrict__ W_tg,
                                               const float* __restrict__ scale,
                                               const float* __restrict__ shift,
                                               ushort* __restrict__ outB) {
    constexpr int K = HID, KPAD = KPAD2;
    __shared__ ushort A_s[96 * KPAD];
    __shared__ ushort W_t[96 * KPAD];
    __shared__ float scs[HID], shs[HID];
    if (threadIdx.x < HID) {
        scs[threadIdx.x] = scale[threadIdx.x];
        shs[threadIdx.x] = shift[threadIdx.x];
    }
    __syncthreads();

    const int rbase = blockIdx.x * 96;
    for (int c = threadIdx.x; c < 96 * (K / 8); c += 384) {
        int row = c / (K / 8), ko = (c - row * (K / 8)) * 8;
        int gr = min(rbase + row, N_NODES - 1);
        uint4 u = *(const uint4*)(X + (size_t)gr * K + ko);
        float4 sA = *(const float4*)&scs[ko], sB = *(const float4*)&scs[ko + 4];
        float4 hA = *(const float4*)&shs[ko], hB = *(const float4*)&shs[ko + 4];
        float v0 = fmaxf(fmaf(bf_lo(u.x), sA.x, hA.x), 0.f);
        float v1 = fmaxf(fmaf(bf_hi(u.x), sA.y, hA.y), 0.f);
        float v2 = fmaxf(fmaf(bf_lo(u.y), sA.z, hA.z), 0.f);
        float v3 = fmaxf(fmaf(bf_hi(u.y), sA.w, hA.w), 0.f);
        float v4 = fmaxf(fmaf(bf_lo(u.z), sB.x, hB.x), 0.f);
        float v5 = fmaxf(fmaf(bf_hi(u.z), sB.y, hB.y), 0.f);
        float v6 = fmaxf(fmaf(bf_lo(u.w), sB.z, hB.z), 0.f);
        float v7 = fmaxf(fmaf(bf_hi(u.w), sB.w, hB.w), 0.f);
        uint4 p;
        p.x = pack2bf(v0, v1);
        p.y = pack2bf(v2, v3);
        p.z = pack2bf(v4, v5);
        p.w = pack2bf(v6, v7);
        *(uint4*)&A_s[row * KPAD + ko] = p;
    }
    for (int i = threadIdx.x; i < 96 * KPAD / 8; i += 384)
        ((uint4*)W_t)[i] = ((const uint4*)W_tg)[i];
    __syncthreads();

    const int lane = threadIdx.x & 63, w = threadIdx.x >> 6;
    const int ar = lane & 15, kg = lane >> 4;
    float4v acc[6] = {};
    const ushort* ap = &A_s[(w * 16 + ar) * KPAD + kg * 8];
    const ushort* bp = &W_t[ar * KPAD + kg * 8];
#pragma unroll
    for (int kc = 0; kc < K / 32; ++kc) {
        short8v af = *(const short8v*)(ap + kc * 32);
#pragma unroll
        for (int ct = 0; ct < 6; ++ct) {
            short8v bfv = *(const short8v*)(bp + ct * 16 * KPAD + kc * 32);
            acc[ct] = __builtin_amdgcn_mfma_f32_16x16x32_bf16(af, bfv, acc[ct], 0, 0, 0);
        }
    }
#pragma unroll
    for (int ct = 0; ct < 6; ++ct) {
        int col = ct * 16 + ar;
#pragma unroll
        for (int i = 0; i < 4; ++i) {
            int grow = rbase + w * 16 + kg * 4 + i;
            if (grow < N_NODES)
                outB[(size_t)grow * HID + col] = f2bf(acc[ct][i]);
        }
    }
}

// ---------------------------------------------------------------------------
// CSR build, contention-free.
// ---------------------------------------------------------------------------
__global__ __launch_bounds__(256) void bin_hist(const int* __restrict__ dst,
                                                int* __restrict__ bcnt) {
    int tile = tile_of(blockIdx.x);
    int beg = tile * TILE_E, end = min(beg + TILE_E, N_EDGES);
    __shared__ int cnt[NBUK];
    for (int b = threadIdx.x; b < NBUK; b += 256) cnt[b] = 0;
    __syncthreads();
    for (int i = beg + threadIdx.x * 4; i < end; i += 256 * 4) {
        int4 d = *(const int4*)(dst + i);
        atomicAdd(&cnt[d.x >> BSHIFT], 1);
        atomicAdd(&cnt[d.y >> BSHIFT], 1);
        atomicAdd(&cnt[d.z >> BSHIFT], 1);
        atomicAdd(&cnt[d.w >> BSHIFT], 1);
    }
    __syncthreads();
    for (int b = threadIdx.x; b < NBUK; b += 256) bcnt[(size_t)b * NBLK_E + tile] = cnt[b];
}

__global__ __launch_bounds__(256) void bin_scanA(const int* __restrict__ bcnt,
                                                 int* __restrict__ boff,
                                                 int* __restrict__ btot) {
    int bin = blockIdx.x, t = threadIdx.x;
    __shared__ int tmp[256];
    int v = (t < NBLK_E) ? bcnt[(size_t)bin * NBLK_E + t] : 0;
    tmp[t] = v;
    __syncthreads();
    for (int off = 1; off < 256; off <<= 1) {
        int a = (t >= off) ? tmp[t - off] : 0;
        __syncthreads();
        tmp[t] += a;
        __syncthreads();
    }
    if (t < NBLK_E) boff[(size_t)bin * NBLK_E + t] = tmp[t] - v;
    if (t == NBLK_E - 1) btot[bin] = tmp[t];
}

__global__ __launch_bounds__(1024) void exscan782(const int* __restrict__ in,
                                                  int* __restrict__ out) {
    int t = threadIdx.x;
    __shared__ int tmp[1024];
    int v = (t < NBUK) ? in[t] : 0;
    tmp[t] = v;
    __syncthreads();
    for (int off = 1; off < 1024; off <<= 1) {
        int a = (t >= off) ? tmp[t - off] : 0;
        __syncthreads();
        tmp[t] += a;
        __syncthreads();
    }
    if (t < NBUK) out[t] = tmp[t] - v;
    if (t == 0) out[NBUK] = N_EDGES;
}

__global__ __launch_bounds__(256) void bin_scatter(const int* __restrict__ src,
                                                   const int* __restrict__ dst,
                                                   const int* __restrict__ bbase,
                                                   const int* __restrict__ boff,
                                                   int* __restrict__ ebuf) {
    int tile = tile_of(blockIdx.x);
    int beg = tile * TILE_E, end = min(beg + TILE_E, N_EDGES);
    __shared__ int curs[NBUK];
    for (int b = threadIdx.x; b < NBUK; b += 256)
        curs[b] = bbase[b] + boff[(size_t)b * NBLK_E + tile];
    __syncthreads();
    for (int i = beg + threadIdx.x * 4; i < end; i += 256 * 4) {
        int4 d = *(const int4*)(dst + i);
        int4 s = *(const int4*)(src + i);
#pragma unroll
        for (int e = 0; e < 4; ++e) {
            int dv = e == 0 ? d.x : e == 1 ? d.y : e == 2 ? d.z : d.w;
            int sv = e == 0 ? s.x : e == 1 ? s.y : e == 2 ? s.z : s.w;
            int p = atomicAdd(&curs[dv >> BSHIFT], 1);
            ebuf[p] = (sv << BSHIFT) | (dv & (BNODES - 1));
        }
    }
}

// merged bucket hist + scan + place (rp base for bucket b == bbase[b])
__global__ __launch_bounds__(256) void bucket_finalize(const int* __restrict__ ebuf,
                                                       const int* __restrict__ bbase,
                                                       int* __restrict__ rp,
                                                       int* __restrict__ cols) {
    int b = blockIdx.x;
    int lo = b << BSHIFT;
    __shared__ int cnt[BNODES];
    __shared__ int cur[BNODES];
    if (threadIdx.x < BNODES) cnt[threadIdx.x] = 0;
    __syncthreads();
    int beg = bbase[b], end = bbase[b + 1];
    for (int i = beg + threadIdx.x; i < end; i += 256)
        atomicAdd(&cnt[ebuf[i] & (BNODES - 1)], 1);
    __syncthreads();
    int t = threadIdx.x;
    int val = (t < BNODES) ? cnt[t] : 0;
    if (t < BNODES) cur[t] = val;
    __syncthreads();
    for (int off = 1; off < BNODES; off <<= 1) {
        int a = (t < BNODES && t >= off) ? cur[t - off] : 0;
        __syncthreads();
        if (t < BNODES) cur[t] += a;
        __syncthreads();
    }
    if (t < BNODES) {
        int excl = beg + cur[t] - val;
        if (lo + t < N_NODES) {
            rp[lo + t] = excl;
            if (lo + t == N_NODES - 1) rp[N_NODES] = N_EDGES;
        }
        cur[t] = excl;
    }
    __syncthreads();
    for (int i = beg + threadIdx.x; i < end; i += 256) {
        int v = ebuf[i];
        int p = atomicAdd(&cur[v & (BNODES - 1)], 1);
        cols[p] = v >> BSHIFT;
    }
}

// ---------------------------------------------------------------------------
// Gather + fused BN stats, 24 lanes/node x 8 B; 8-wide neighbor unroll.
// cols loaded NON-TEMPORAL (evict-first) so the 6.4 MB stream doesn't evict
// the T table's L2 lines (T is the only reused data; 47% hit measured).
// ---------------------------------------------------------------------------
#define GLANES 24
#define GNODES 8  // 192 threads / 24 lanes

__global__ __launch_bounds__(192) void gather_stats(const ushort* __restrict__ T,
                                                    const int* __restrict__ rp,
                                                    const int* __restrict__ cols,
                                                    const float* __restrict__ bias,
                                                    ushort* __restrict__ z,
                                                    float* __restrict__ psums,
                                                    float* __restrict__ psq) {
    const int q = threadIdx.x % GLANES;
    const int rs = threadIdx.x / GLANES;
    const float4 bias4 = ((const float4*)bias)[q];
    float4 s = make_float4(0.f, 0.f, 0.f, 0.f);
    float4 sq = make_float4(0.f, 0.f, 0.f, 0.f);

#define ADDROW(u)                                                              \
    {                                                                          \
        ushort4 w = *(const ushort4*)(T + (size_t)(u) * HID + q * 4);          \
        a.x += bf2f(w.x); a.y += bf2f(w.y);                                    \
        a.z += bf2f(w.z); a.w += bf2f(w.w);                                    \
    }
#define NTC(j) __builtin_nontemporal_load(cols + (j))

    for (int v = blockIdx.x * GNODES + rs; v < N_NODES; v += NB_GATH * GNODES) {
        float4 a = bias4;
        ADDROW(v);
        int beg = rp[v], end = rp[v + 1];
        int j = beg;
        for (; j + 7 < end; j += 8) {
            int u0 = NTC(j), u1 = NTC(j + 1), u2 = NTC(j + 2), u3 = NTC(j + 3);
            int u4 = NTC(j + 4), u5 = NTC(j + 5), u6 = NTC(j + 6), u7 = NTC(j + 7);
            ADDROW(u0); ADDROW(u1); ADDROW(u2); ADDROW(u3);
            ADDROW(u4); ADDROW(u5); ADDROW(u6); ADDROW(u7);
        }
        for (; j + 3 < end; j += 4) {
            int u0 = NTC(j), u1 = NTC(j + 1), u2 = NTC(j + 2), u3 = NTC(j + 3);
            ADDROW(u0); ADDROW(u1); ADDROW(u2); ADDROW(u3);
        }
        for (; j < end; ++j) { int u = NTC(j); ADDROW(u); }

        uint2 o;
        o.x = pack2bf(a.x, a.y);
        o.y = pack2bf(a.z, a.w);
        *(uint2*)(z + (size_t)v * HID + q * 4) = o;
        s.x += a.x; s.y += a.y; s.z += a.z; s.w += a.w;
        sq.x = fmaf(a.x, a.x, sq.x);
        sq.y = fmaf(a.y, a.y, sq.y);
        sq.z = fmaf(a.z, a.z, sq.z);
        sq.w = fmaf(a.w, a.w, sq.w);
    }
#undef ADDROW
#undef NTC

    __shared__ float4 ls[GNODES][GLANES], lq[GNODES][GLANES];
    ls[rs][q] = s;
    lq[rs][q] = sq;
    __syncthreads();
    if (threadIdx.x < GLANES) {
        float4 S = ls[0][threadIdx.x], Q = lq[0][threadIdx.x];
#pragma unroll
        for (int i = 1; i < GNODES; ++i) {
            S.x += ls[i][threadIdx.x].x; S.y += ls[i][threadIdx.x].y;
            S.z += ls[i][threadIdx.x].z; S.w += ls[i][threadIdx.x].w;
            Q.x += lq[i][threadIdx.x].x; Q.y += lq[i][threadIdx.x].y;
            Q.z += lq[i][threadIdx.x].z; Q.w += lq[i][threadIdx.x].w;
        }
        ((float4*)(psums + (size_t)blockIdx.x * HID))[threadIdx.x] = S;
        ((float4*)(psq + (size_t)blockIdx.x * HID))[threadIdx.x] = Q;
    }
}

// ---------------------------------------------------------------------------
__global__ __launch_bounds__(384) void bn_finalize(const float* __restrict__ psums,
                                                   const float* __restrict__ psq,
                                                   const float* __restrict__ g,
                                                   const float* __restrict__ be,
                                                   float* __restrict__ scale,
                                                   float* __restrict__ shift) {
    int c = threadIdx.x % 96, h = threadIdx.x / 96;
    float S = 0.f, Q = 0.f;
    for (int b = h * (NB_GATH / 4); b < (h + 1) * (NB_GATH / 4); ++b) {
        S += psums[(size_t)b * HID + c];
        Q += psq[(size_t)b * HID + c];
    }
    __shared__ float lS[4][96], lQ[4][96];
    lS[h][c] = S;
    lQ[h][c] = Q;
    __syncthreads();
    if (threadIdx.x < 96) {
        S = lS[0][c] + lS[1][c] + lS[2][c] + lS[3][c];
        Q = lQ[0][c] + lQ[1][c] + lQ[2][c] + lQ[3][c];
        float mu = S * (1.0f / N_NODES);
        float var = Q * (1.0f / N_NODES) - mu * mu;
        float rstd = rsqrtf(var + 1e-5f);
        float sc = g[c] * rstd;
        scale[c] = sc;
        shift[c] = be[c] - mu * sc;
    }
}

// ---------------------------------------------------------------------------
// Readout: bf16 input, BN2+ReLU fused during LDS staging, 16 lanes/row
// shuffle log_softmax, coalesced store.
// ---------------------------------------------------------------------------
__global__ __launch_bounds__(256) void readout_kernel(const ushort* __restrict__ X,
                                                      const float* __restrict__ scale,
                                                      const float* __restrict__ shift,
                                                      const float* __restrict__ Wr,
                                                      const float* __restrict__ br,
                                                      float* __restrict__ out) {
    __shared__ float Ws[HID * NCLS];
    __shared__ float XL[16 * 97];
    __shared__ float scs[HID], shs[HID], bs[NCLS];
    for (int i = threadIdx.x; i < HID * NCLS / 4; i += 256)
        ((float4*)Ws)[i] = ((const float4*)Wr)[i];
    if (threadIdx.x < HID) {
        scs[threadIdx.x] = scale[threadIdx.x];
        shs[threadIdx.x] = shift[threadIdx.x];
    }
    if (threadIdx.x < NCLS) bs[threadIdx.x] = br[threadIdx.x];

    int rr = threadIdx.x >> 4, t = threadIdx.x & 15;
    for (int tile = blockIdx.x; tile < N_NODES / 16; tile += gridDim.x) {
        int rbase = tile * 16;
        __syncthreads();
        if (threadIdx.x < 192) {
            int base = threadIdx.x * 8;
            int row = base / HID, col = base - (base / HID) * HID;
            uint4 w = *(const uint4*)(X + (size_t)rbase * HID + base);
            float v[8] = {bf_lo(w.x), bf_hi(w.x), bf_lo(w.y), bf_hi(w.y),
                          bf_lo(w.z), bf_hi(w.z), bf_lo(w.w), bf_hi(w.w)};
#pragma unroll
            for (int e = 0; e < 8; ++e)
                XL[row * 97 + col + e] = fmaxf(fmaf(v[e], scs[col + e], shs[col + e]), 0.f);
        }
        __syncthreads();
        float acc = bs[t];
        const float* xrow = &XL[rr * 97];
#pragma unroll 4
        for (int k = 0; k < HID; ++k) acc = fmaf(xrow[k], Ws[k * NCLS + t], acc);
        float m = acc;
#pragma unroll
        for (int off = 8; off; off >>= 1) m = fmaxf(m, __shfl_xor(m, off, 16));
        float e = expf(acc - m);
        float sum = e;
#pragma unroll
        for (int off = 8; off; off >>= 1) sum += __shfl_xor(sum, off, 16);
        float lse = m + logf(sum);
        out[(size_t)rbase * NCLS + threadIdx.x] = acc - lse;
    }
}

// ---------------------------------------------------------------------------
extern "C" void kernel_launch(void* const* d_in, const int* in_sizes, int n_in,
                              void* d_out, int out_size, void* d_ws, size_t ws_size,
                              hipStream_t stream) {
    const float* h     = (const float*)d_in[0];
    const int*   src   = (const int*)d_in[1];
    const int*   dst   = (const int*)d_in[2];
    const float* W_emb = (const float*)d_in[3];
    const float* b_emb = (const float*)d_in[4];
    const float* W1    = (const float*)d_in[5];
    const float* b1    = (const float*)d_in[6];
    const float* g1    = (const float*)d_in[7];
    const float* be1   = (const float*)d_in[8];
    const float* W2    = (const float*)d_in[9];
    const float* b2    = (const float*)d_in[10];
    const float* g2    = (const float*)d_in[11];
    const float* be2   = (const float*)d_in[12];
    const float* Wr    = (const float*)d_in[13];
    const float* br    = (const float*)d_in[14];

    const size_t nh = (size_t)N_NODES * HID;
    ushort* z    = (ushort*)d_ws;             // 19.2 MB bf16 (z1, then z2)
    ushort* T    = z + nh;                    // 19.2 MB bf16 table
    int* rp      = (int*)(T + nh);            // N+1
    int* cols    = rp + N_NODES + 1;          // E
    int* ebuf    = cols + N_EDGES;            // E
    int* bcnt    = ebuf + N_EDGES;            // NBUK*NBLK_E
    int* boff    = bcnt + NBUK * NBLK_E;      // NBUK*NBLK_E
    int* btot    = boff + NBUK * NBLK_E;      // NBUK
    int* bbase   = btot + NBUK;               // NBUK+1
    float* psums = (float*)(bbase + NBUK + 1);  // NB_GATH*96
    float* psq   = psums + (size_t)NB_GATH * HID;
    float* scale = psq + (size_t)NB_GATH * HID;   // 96
    float* shift = scale + HID;                    // 96
    ushort* Wt1  = (ushort*)(shift + HID);         // 96*KPAD1
    ushort* Wt2  = Wt1 + 96 * KPAD1;               // 96*KPAD2
    float* bf    = (float*)(Wt2 + 96 * KPAD2 + (96 * KPAD2 & 1));  // 96

    const int blkT = (N_NODES + 95) / 96;     // 1042

    // --- CSR build + weight prep ---
    bin_hist<<<NBLK_E, 256, 0, stream>>>(dst, bcnt);
    bin_scanA<<<NBUK, 256, 0, stream>>>(bcnt, boff, btot);
    exscan782<<<1, 1024, 0, stream>>>(btot, bbase);
    bin_scatter<<<NBLK_E, 256, 0, stream>>>(src, dst, bbase, boff, ebuf);
    bucket_finalize<<<NBUK, 256, 0, stream>>>(ebuf, bbase, rp, cols);
    wfuse<<<(IN_DIM * HID + 255) / 256, 256, 0, stream>>>(W_emb, W1, b_emb, W2,
                                                          Wt1, Wt2, bf);

    // --- layer 1: T1 = h @ Wf + bf (bf16, MFMA);  z1 = gather(T1) + b1 ---
    gemm_l1<<<blkT, 384, 0, stream>>>(h, Wt1, bf, T);
    gather_stats<<<NB_GATH, 192, 0, stream>>>(T, rp, cols, b1, z, psums, psq);
    bn_finalize<<<1, 384, 0, stream>>>(psums, psq, g1, be1, scale, shift);

    // --- layer 2: T2 = relu(bn1(z1)) @ W2 (bf16, MFMA);  z2 = gather + b2 ---
    gemm_l2<<<blkT, 384, 0, stream>>>(z, Wt2, scale, shift, T);
    gather_stats<<<NB_GATH, 192, 0, stream>>>(T, rp, cols, b2, z, psums, psq);
    bn_finalize<<<1, 384, 0, stream>>>(psums, psq, g2, be2, scale, shift);

    // --- readout (BN2+ReLU fused) + log_softmax ---
    readout_kernel<<<2048, 256, 0, stream>>>(z, scale, shift, Wr, br, (float*)d_out);
}

// Round 18
// 304.262 us; speedup vs baseline: 1.0323x; 1.0323x over previous
//
#include <hip/hip_runtime.h>
#include <cmath>

#define N_NODES 100000
#define N_EDGES 1600000
#define IN_DIM 128
#define HID 96
#define NCLS 16
#define NB_GATH 2560  // gather grid (fixed, for stats partials)

// bucket-sort CSR build (contention-free)
#define BSHIFT 7
#define BNODES 128
#define NBUK 782
#define TILE_E 8192
#define NBLK_E 196
#define NBLK_Q 24
#define NBLK_R 4

#define KPAD1 (IN_DIM + 8)   // 136
#define KPAD2 (HID + 8)      // 104

typedef unsigned int uint;
typedef unsigned short ushort;
typedef __attribute__((ext_vector_type(8))) short short8v;
typedef __attribute__((ext_vector_type(4))) float float4v;

__device__ __forceinline__ ushort f2bf(float x) {  // RNE f32->bf16
    uint b = __float_as_uint(x);
    uint r = (b + 0x7FFFu + ((b >> 16) & 1u)) >> 16;
    return (ushort)r;
}
__device__ __forceinline__ float bf2f(ushort u) {
    return __uint_as_float(((uint)u) << 16);
}
__device__ __forceinline__ float bf_lo(uint w) { return __uint_as_float(w << 16); }
__device__ __forceinline__ float bf_hi(uint w) { return __uint_as_float(w & 0xFFFF0000u); }
__device__ __forceinline__ uint pack2bf(float a, float b) {
    return (uint)f2bf(a) | ((uint)f2bf(b) << 16);
}

// XCD-swizzled tile mapping (bijective for NBLK_E = 8*NBLK_Q + NBLK_R).
__device__ __forceinline__ int tile_of(int blk) {
    int xcd = blk & 7, slot = blk >> 3;
    return (xcd < NBLK_R) ? xcd * (NBLK_Q + 1) + slot
                          : NBLK_R * (NBLK_Q + 1) + (xcd - NBLK_R) * NBLK_Q + slot;
}

// ---------------------------------------------------------------------------
// wfuse: W_t1[n][k] = bf16((W_emb @ W1)[k][n]); bf = b_emb @ W1;
// also W_t2[n][k] = bf16(W2[k][n]). All weight prep in ONE dispatch.
// ---------------------------------------------------------------------------
__global__ __launch_bounds__(256) void wfuse(const float* __restrict__ W_emb,
                                             const float* __restrict__ W1,
                                             const float* __restrict__ b_emb,
                                             const float* __restrict__ W2,
                                             ushort* __restrict__ W_t1,
                                             ushort* __restrict__ W_t2,
                                             float* __restrict__ bf) {
    __shared__ float W1s[HID * HID];
    for (int i = threadIdx.x; i < HID * HID / 4; i += 256)
        ((float4*)W1s)[i] = ((const float4*)W1)[i];
    __syncthreads();
    int idx = blockIdx.x * 256 + threadIdx.x;
    if (idx < IN_DIM * HID) {
        int i = idx / HID, j = idx - (idx / HID) * HID;
        float acc = 0.f;
        for (int k = 0; k < HID; ++k)
            acc = fmaf(W_emb[(size_t)i * HID + k], W1s[k * HID + j], acc);
        W_t1[(size_t)j * KPAD1 + i] = f2bf(acc);
    }
    if (idx < HID * HID) {
        int k = idx / HID, n = idx - (idx / HID) * HID;
        W_t2[(size_t)n * KPAD2 + k] = f2bf(W2[idx]);
    }
    if (idx < HID) {
        float acc = 0.f;
        for (int k = 0; k < HID; ++k)
            acc = fmaf(b_emb[k], W1s[k * HID + idx], acc);
        bf[idx] = acc;
    }
}

// ---------------------------------------------------------------------------
// MFMA layer-1 GEMM: T1 = bf16(X) @ Wf + bf -> bf16 table.
// ---------------------------------------------------------------------------
__global__ __launch_bounds__(384) void gemm_l1(const float* __restrict__ X,
                                               const ushort* __restrict__ W_tg,
                                               const float* __restrict__ bias,
                                               ushort* __restrict__ outB) {
    constexpr int K = IN_DIM, KPAD = KPAD1;
    __shared__ ushort A_s[96 * KPAD];
    __shared__ ushort W_t[96 * KPAD];
    __shared__ float bs[HID];
    if (threadIdx.x < HID) bs[threadIdx.x] = bias[threadIdx.x];

    const int rbase = blockIdx.x * 96;
    for (int c = threadIdx.x; c < 96 * (K / 8); c += 384) {
        int row = c / (K / 8), ko = (c - row * (K / 8)) * 8;
        int gr = min(rbase + row, N_NODES - 1);
        const float* xp = X + (size_t)gr * K + ko;
        float4 v0 = *(const float4*)xp;
        float4 v1 = *(const float4*)(xp + 4);
        uint4 p;
        p.x = pack2bf(v0.x, v0.y);
        p.y = pack2bf(v0.z, v0.w);
        p.z = pack2bf(v1.x, v1.y);
        p.w = pack2bf(v1.z, v1.w);
        *(uint4*)&A_s[row * KPAD + ko] = p;
    }
    for (int i = threadIdx.x; i < 96 * KPAD / 8; i += 384)
        ((uint4*)W_t)[i] = ((const uint4*)W_tg)[i];
    __syncthreads();

    const int lane = threadIdx.x & 63, w = threadIdx.x >> 6;
    const int ar = lane & 15, kg = lane >> 4;
    float4v acc[6] = {};
    const ushort* ap = &A_s[(w * 16 + ar) * KPAD + kg * 8];
    const ushort* bp = &W_t[ar * KPAD + kg * 8];
#pragma unroll
    for (int kc = 0; kc < K / 32; ++kc) {
        short8v af = *(const short8v*)(ap + kc * 32);
#pragma unroll
        for (int ct = 0; ct < 6; ++ct) {
            short8v bfv = *(const short8v*)(bp + ct * 16 * KPAD + kc * 32);
            acc[ct] = __builtin_amdgcn_mfma_f32_16x16x32_bf16(af, bfv, acc[ct], 0, 0, 0);
        }
    }
#pragma unroll
    for (int ct = 0; ct < 6; ++ct) {
        int col = ct * 16 + ar;
        float bb = bs[col];
#pragma unroll
        for (int i = 0; i < 4; ++i) {
            int grow = rbase + w * 16 + kg * 4 + i;
            if (grow < N_NODES)
                outB[(size_t)grow * HID + col] = f2bf(acc[ct][i] + bb);
        }
    }
}

// ---------------------------------------------------------------------------
// MFMA layer-2 GEMM: T2 = relu(bn1(z1)) @ W2 -> bf16 (BN+ReLU at A-staging).
// ---------------------------------------------------------------------------
__global__ __launch_bounds__(384) void gemm_l2(const ushort* __restrict__ X,
                                               const ushort* __restrict__ W_tg,
                                               const float* __restrict__ scale,
                                               const float* __restrict__ shift,
                                               ushort* __restrict__ outB) {
    constexpr int K = HID, KPAD = KPAD2;
    __shared__ ushort A_s[96 * KPAD];
    __shared__ ushort W_t[96 * KPAD];
    __shared__ float scs[HID], shs[HID];
    if (threadIdx.x < HID) {
        scs[threadIdx.x] = scale[threadIdx.x];
        shs[threadIdx.x] = shift[threadIdx.x];
    }
    __syncthreads();

    const int rbase = blockIdx.x * 96;
    for (int c = threadIdx.x; c < 96 * (K / 8); c += 384) {
        int row = c / (K / 8), ko = (c - row * (K / 8)) * 8;
        int gr = min(rbase + row, N_NODES - 1);
        uint4 u = *(const uint4*)(X + (size_t)gr * K + ko);
        float4 sA = *(const float4*)&scs[ko], sB = *(const float4*)&scs[ko + 4];
        float4 hA = *(const float4*)&shs[ko], hB = *(const float4*)&shs[ko + 4];
        float v0 = fmaxf(fmaf(bf_lo(u.x), sA.x, hA.x), 0.f);
        float v1 = fmaxf(fmaf(bf_hi(u.x), sA.y, hA.y), 0.f);
        float v2 = fmaxf(fmaf(bf_lo(u.y), sA.z, hA.z), 0.f);
        float v3 = fmaxf(fmaf(bf_hi(u.y), sA.w, hA.w), 0.f);
        float v4 = fmaxf(fmaf(bf_lo(u.z), sB.x, hB.x), 0.f);
        float v5 = fmaxf(fmaf(bf_hi(u.z), sB.y, hB.y), 0.f);
        float v6 = fmaxf(fmaf(bf_lo(u.w), sB.z, hB.z), 0.f);
        float v7 = fmaxf(fmaf(bf_hi(u.w), sB.w, hB.w), 0.f);
        uint4 p;
        p.x = pack2bf(v0, v1);
        p.y = pack2bf(v2, v3);
        p.z = pack2bf(v4, v5);
        p.w = pack2bf(v6, v7);
        *(uint4*)&A_s[row * KPAD + ko] = p;
    }
    for (int i = threadIdx.x; i < 96 * KPAD / 8; i += 384)
        ((uint4*)W_t)[i] = ((const uint4*)W_tg)[i];
    __syncthreads();

    const int lane = threadIdx.x & 63, w = threadIdx.x >> 6;
    const int ar = lane & 15, kg = lane >> 4;
    float4v acc[6] = {};
    const ushort* ap = &A_s[(w * 16 + ar) * KPAD + kg * 8];
    const ushort* bp = &W_t[ar * KPAD + kg * 8];
#pragma unroll
    for (int kc = 0; kc < K / 32; ++kc) {
        short8v af = *(const short8v*)(ap + kc * 32);
#pragma unroll
        for (int ct = 0; ct < 6; ++ct) {
            short8v bfv = *(const short8v*)(bp + ct * 16 * KPAD + kc * 32);
            acc[ct] = __builtin_amdgcn_mfma_f32_16x16x32_bf16(af, bfv, acc[ct], 0, 0, 0);
        }
    }
#pragma unroll
    for (int ct = 0; ct < 6; ++ct) {
        int col = ct * 16 + ar;
#pragma unroll
        for (int i = 0; i < 4; ++i) {
            int grow = rbase + w * 16 + kg * 4 + i;
            if (grow < N_NODES)
                outB[(size_t)grow * HID + col] = f2bf(acc[ct][i]);
        }
    }
}

// ---------------------------------------------------------------------------
// CSR build, contention-free.
// ---------------------------------------------------------------------------
__global__ __launch_bounds__(256) void bin_hist(const int* __restrict__ dst,
                                                int* __restrict__ bcnt) {
    int tile = tile_of(blockIdx.x);
    int beg = tile * TILE_E, end = min(beg + TILE_E, N_EDGES);
    __shared__ int cnt[NBUK];
    for (int b = threadIdx.x; b < NBUK; b += 256) cnt[b] = 0;
    __syncthreads();
    for (int i = beg + threadIdx.x * 4; i < end; i += 256 * 4) {
        int4 d = *(const int4*)(dst + i);
        atomicAdd(&cnt[d.x >> BSHIFT], 1);
        atomicAdd(&cnt[d.y >> BSHIFT], 1);
        atomicAdd(&cnt[d.z >> BSHIFT], 1);
        atomicAdd(&cnt[d.w >> BSHIFT], 1);
    }
    __syncthreads();
    for (int b = threadIdx.x; b < NBUK; b += 256) bcnt[(size_t)b * NBLK_E + tile] = cnt[b];
}

__global__ __launch_bounds__(256) void bin_scanA(const int* __restrict__ bcnt,
                                                 int* __restrict__ boff,
                                                 int* __restrict__ btot) {
    int bin = blockIdx.x, t = threadIdx.x;
    __shared__ int tmp[256];
    int v = (t < NBLK_E) ? bcnt[(size_t)bin * NBLK_E + t] : 0;
    tmp[t] = v;
    __syncthreads();
    for (int off = 1; off < 256; off <<= 1) {
        int a = (t >= off) ? tmp[t - off] : 0;
        __syncthreads();
        tmp[t] += a;
        __syncthreads();
    }
    if (t < NBLK_E) boff[(size_t)bin * NBLK_E + t] = tmp[t] - v;
    if (t == NBLK_E - 1) btot[bin] = tmp[t];
}

__global__ __launch_bounds__(1024) void exscan782(const int* __restrict__ in,
                                                  int* __restrict__ out) {
    int t = threadIdx.x;
    __shared__ int tmp[1024];
    int v = (t < NBUK) ? in[t] : 0;
    tmp[t] = v;
    __syncthreads();
    for (int off = 1; off < 1024; off <<= 1) {
        int a = (t >= off) ? tmp[t - off] : 0;
        __syncthreads();
        tmp[t] += a;
        __syncthreads();
    }
    if (t < NBUK) out[t] = tmp[t] - v;
    if (t == 0) out[NBUK] = N_EDGES;
}

__global__ __launch_bounds__(256) void bin_scatter(const int* __restrict__ src,
                                                   const int* __restrict__ dst,
                                                   const int* __restrict__ bbase,
                                                   const int* __restrict__ boff,
                                                   int* __restrict__ ebuf) {
    int tile = tile_of(blockIdx.x);
    int beg = tile * TILE_E, end = min(beg + TILE_E, N_EDGES);
    __shared__ int curs[NBUK];
    for (int b = threadIdx.x; b < NBUK; b += 256)
        curs[b] = bbase[b] + boff[(size_t)b * NBLK_E + tile];
    __syncthreads();
    for (int i = beg + threadIdx.x * 4; i < end; i += 256 * 4) {
        int4 d = *(const int4*)(dst + i);
        int4 s = *(const int4*)(src + i);
#pragma unroll
        for (int e = 0; e < 4; ++e) {
            int dv = e == 0 ? d.x : e == 1 ? d.y : e == 2 ? d.z : d.w;
            int sv = e == 0 ? s.x : e == 1 ? s.y : e == 2 ? s.z : s.w;
            int p = atomicAdd(&curs[dv >> BSHIFT], 1);
            ebuf[p] = (sv << BSHIFT) | (dv & (BNODES - 1));
        }
    }
}

// merged bucket hist + scan + place (rp base for bucket b == bbase[b])
__global__ __launch_bounds__(256) void bucket_finalize(const int* __restrict__ ebuf,
                                                       const int* __restrict__ bbase,
                                                       int* __restrict__ rp,
                                                       int* __restrict__ cols) {
    int b = blockIdx.x;
    int lo = b << BSHIFT;
    __shared__ int cnt[BNODES];
    __shared__ int cur[BNODES];
    if (threadIdx.x < BNODES) cnt[threadIdx.x] = 0;
    __syncthreads();
    int beg = bbase[b], end = bbase[b + 1];
    for (int i = beg + threadIdx.x; i < end; i += 256)
        atomicAdd(&cnt[ebuf[i] & (BNODES - 1)], 1);
    __syncthreads();
    int t = threadIdx.x;
    int val = (t < BNODES) ? cnt[t] : 0;
    if (t < BNODES) cur[t] = val;
    __syncthreads();
    for (int off = 1; off < BNODES; off <<= 1) {
        int a = (t < BNODES && t >= off) ? cur[t - off] : 0;
        __syncthreads();
        if (t < BNODES) cur[t] += a;
        __syncthreads();
    }
    if (t < BNODES) {
        int excl = beg + cur[t] - val;
        if (lo + t < N_NODES) {
            rp[lo + t] = excl;
            if (lo + t == N_NODES - 1) rp[N_NODES] = N_EDGES;
        }
        cur[t] = excl;
    }
    __syncthreads();
    for (int i = beg + threadIdx.x; i < end; i += 256) {
        int v = ebuf[i];
        int p = atomicAdd(&cur[v & (BNODES - 1)], 1);
        cols[p] = v >> BSHIFT;
    }
}

// ---------------------------------------------------------------------------
// Gather + fused BN stats, 24 lanes/node x 8 B; 8-wide neighbor unroll.
// cols via CACHED loads (round-17 nt experiment regressed: evict-first
// dropped half-consumed cols lines, +12 MB refetch).
// ---------------------------------------------------------------------------
#define GLANES 24
#define GNODES 8  // 192 threads / 24 lanes

__global__ __launch_bounds__(192) void gather_stats(const ushort* __restrict__ T,
                                                    const int* __restrict__ rp,
                                                    const int* __restrict__ cols,
                                                    const float* __restrict__ bias,
                                                    ushort* __restrict__ z,
                                                    float* __restrict__ psums,
                                                    float* __restrict__ psq) {
    const int q = threadIdx.x % GLANES;
    const int rs = threadIdx.x / GLANES;
    const float4 bias4 = ((const float4*)bias)[q];
    float4 s = make_float4(0.f, 0.f, 0.f, 0.f);
    float4 sq = make_float4(0.f, 0.f, 0.f, 0.f);

#define ADDROW(u)                                                              \
    {                                                                          \
        ushort4 w = *(const ushort4*)(T + (size_t)(u) * HID + q * 4);          \
        a.x += bf2f(w.x); a.y += bf2f(w.y);                                    \
        a.z += bf2f(w.z); a.w += bf2f(w.w);                                    \
    }

    for (int v = blockIdx.x * GNODES + rs; v < N_NODES; v += NB_GATH * GNODES) {
        float4 a = bias4;
        ADDROW(v);
        int beg = rp[v], end = rp[v + 1];
        int j = beg;
        for (; j + 7 < end; j += 8) {
            int u0 = cols[j], u1 = cols[j + 1], u2 = cols[j + 2], u3 = cols[j + 3];
            int u4 = cols[j + 4], u5 = cols[j + 5], u6 = cols[j + 6], u7 = cols[j + 7];
            ADDROW(u0); ADDROW(u1); ADDROW(u2); ADDROW(u3);
            ADDROW(u4); ADDROW(u5); ADDROW(u6); ADDROW(u7);
        }
        for (; j + 3 < end; j += 4) {
            int u0 = cols[j], u1 = cols[j + 1], u2 = cols[j + 2], u3 = cols[j + 3];
            ADDROW(u0); ADDROW(u1); ADDROW(u2); ADDROW(u3);
        }
        for (; j < end; ++j) ADDROW(cols[j]);

        uint2 o;
        o.x = pack2bf(a.x, a.y);
        o.y = pack2bf(a.z, a.w);
        *(uint2*)(z + (size_t)v * HID + q * 4) = o;
        s.x += a.x; s.y += a.y; s.z += a.z; s.w += a.w;
        sq.x = fmaf(a.x, a.x, sq.x);
        sq.y = fmaf(a.y, a.y, sq.y);
        sq.z = fmaf(a.z, a.z, sq.z);
        sq.w = fmaf(a.w, a.w, sq.w);
    }
#undef ADDROW

    __shared__ float4 ls[GNODES][GLANES], lq[GNODES][GLANES];
    ls[rs][q] = s;
    lq[rs][q] = sq;
    __syncthreads();
    if (threadIdx.x < GLANES) {
        float4 S = ls[0][threadIdx.x], Q = lq[0][threadIdx.x];
#pragma unroll
        for (int i = 1; i < GNODES; ++i) {
            S.x += ls[i][threadIdx.x].x; S.y += ls[i][threadIdx.x].y;
            S.z += ls[i][threadIdx.x].z; S.w += ls[i][threadIdx.x].w;
            Q.x += lq[i][threadIdx.x].x; Q.y += lq[i][threadIdx.x].y;
            Q.z += lq[i][threadIdx.x].z; Q.w += lq[i][threadIdx.x].w;
        }
        ((float4*)(psums + (size_t)blockIdx.x * HID))[threadIdx.x] = S;
        ((float4*)(psq + (size_t)blockIdx.x * HID))[threadIdx.x] = Q;
    }
}

// ---------------------------------------------------------------------------
__global__ __launch_bounds__(384) void bn_finalize(const float* __restrict__ psums,
                                                   const float* __restrict__ psq,
                                                   const float* __restrict__ g,
                                                   const float* __restrict__ be,
                                                   float* __restrict__ scale,
                                                   float* __restrict__ shift) {
    int c = threadIdx.x % 96, h = threadIdx.x / 96;
    float S = 0.f, Q = 0.f;
    for (int b = h * (NB_GATH / 4); b < (h + 1) * (NB_GATH / 4); ++b) {
        S += psums[(size_t)b * HID + c];
        Q += psq[(size_t)b * HID + c];
    }
    __shared__ float lS[4][96], lQ[4][96];
    lS[h][c] = S;
    lQ[h][c] = Q;
    __syncthreads();
    if (threadIdx.x < 96) {
        S = lS[0][c] + lS[1][c] + lS[2][c] + lS[3][c];
        Q = lQ[0][c] + lQ[1][c] + lQ[2][c] + lQ[3][c];
        float mu = S * (1.0f / N_NODES);
        float var = Q * (1.0f / N_NODES) - mu * mu;
        float rstd = rsqrtf(var + 1e-5f);
        float sc = g[c] * rstd;
        scale[c] = sc;
        shift[c] = be[c] - mu * sc;
    }
}

// ---------------------------------------------------------------------------
// Readout: bf16 input, BN2+ReLU fused during LDS staging, 16 lanes/row
// shuffle log_softmax, coalesced store.
// ---------------------------------------------------------------------------
__global__ __launch_bounds__(256) void readout_kernel(const ushort* __restrict__ X,
                                                      const float* __restrict__ scale,
                                                      const float* __restrict__ shift,
                                                      const float* __restrict__ Wr,
                                                      const float* __restrict__ br,
                                                      float* __restrict__ out) {
    __shared__ float Ws[HID * NCLS];
    __shared__ float XL[16 * 97];
    __shared__ float scs[HID], shs[HID], bs[NCLS];
    for (int i = threadIdx.x; i < HID * NCLS / 4; i += 256)
        ((float4*)Ws)[i] = ((const float4*)Wr)[i];
    if (threadIdx.x < HID) {
        scs[threadIdx.x] = scale[threadIdx.x];
        shs[threadIdx.x] = shift[threadIdx.x];
    }
    if (threadIdx.x < NCLS) bs[threadIdx.x] = br[threadIdx.x];

    int rr = threadIdx.x >> 4, t = threadIdx.x & 15;
    for (int tile = blockIdx.x; tile < N_NODES / 16; tile += gridDim.x) {
        int rbase = tile * 16;
        __syncthreads();
        if (threadIdx.x < 192) {
            int base = threadIdx.x * 8;
            int row = base / HID, col = base - (base / HID) * HID;
            uint4 w = *(const uint4*)(X + (size_t)rbase * HID + base);
            float v[8] = {bf_lo(w.x), bf_hi(w.x), bf_lo(w.y), bf_hi(w.y),
                          bf_lo(w.z), bf_hi(w.z), bf_lo(w.w), bf_hi(w.w)};
#pragma unroll
            for (int e = 0; e < 8; ++e)
                XL[row * 97 + col + e] = fmaxf(fmaf(v[e], scs[col + e], shs[col + e]), 0.f);
        }
        __syncthreads();
        float acc = bs[t];
        const float* xrow = &XL[rr * 97];
#pragma unroll 4
        for (int k = 0; k < HID; ++k) acc = fmaf(xrow[k], Ws[k * NCLS + t], acc);
        float m = acc;
#pragma unroll
        for (int off = 8; off; off >>= 1) m = fmaxf(m, __shfl_xor(m, off, 16));
        float e = expf(acc - m);
        float sum = e;
#pragma unroll
        for (int off = 8; off; off >>= 1) sum += __shfl_xor(sum, off, 16);
        float lse = m + logf(sum);
        out[(size_t)rbase * NCLS + threadIdx.x] = acc - lse;
    }
}

// ---------------------------------------------------------------------------
extern "C" void kernel_launch(void* const* d_in, const int* in_sizes, int n_in,
                              void* d_out, int out_size, void* d_ws, size_t ws_size,
                              hipStream_t stream) {
    const float* h     = (const float*)d_in[0];
    const int*   src   = (const int*)d_in[1];
    const int*   dst   = (const int*)d_in[2];
    const float* W_emb = (const float*)d_in[3];
    const float* b_emb = (const float*)d_in[4];
    const float* W1    = (const float*)d_in[5];
    const float* b1    = (const float*)d_in[6];
    const float* g1    = (const float*)d_in[7];
    const float* be1   = (const float*)d_in[8];
    const float* W2    = (const float*)d_in[9];
    const float* b2    = (const float*)d_in[10];
    const float* g2    = (const float*)d_in[11];
    const float* be2   = (const float*)d_in[12];
    const float* Wr    = (const float*)d_in[13];
    const float* br    = (const float*)d_in[14];

    const size_t nh = (size_t)N_NODES * HID;
    ushort* z    = (ushort*)d_ws;             // 19.2 MB bf16 (z1, then z2)
    ushort* T    = z + nh;                    // 19.2 MB bf16 table
    int* rp      = (int*)(T + nh);            // N+1
    int* cols    = rp + N_NODES + 1;          // E
    int* ebuf    = cols + N_EDGES;            // E
    int* bcnt    = ebuf + N_EDGES;            // NBUK*NBLK_E
    int* boff    = bcnt + NBUK * NBLK_E;      // NBUK*NBLK_E
    int* btot    = boff + NBUK * NBLK_E;      // NBUK
    int* bbase   = btot + NBUK;               // NBUK+1
    float* psums = (float*)(bbase + NBUK + 1);  // NB_GATH*96
    float* psq   = psums + (size_t)NB_GATH * HID;
    float* scale = psq + (size_t)NB_GATH * HID;   // 96
    float* shift = scale + HID;                    // 96
    ushort* Wt1  = (ushort*)(shift + HID);         // 96*KPAD1
    ushort* Wt2  = Wt1 + 96 * KPAD1;               // 96*KPAD2
    float* bf    = (float*)(Wt2 + 96 * KPAD2 + (96 * KPAD2 & 1));  // 96

    const int blkT = (N_NODES + 95) / 96;     // 1042

    // --- CSR build + weight prep ---
    bin_hist<<<NBLK_E, 256, 0, stream>>>(dst, bcnt);
    bin_scanA<<<NBUK, 256, 0, stream>>>(bcnt, boff, btot);
    exscan782<<<1, 1024, 0, stream>>>(btot, bbase);
    bin_scatter<<<NBLK_E, 256, 0, stream>>>(src, dst, bbase, boff, ebuf);
    bucket_finalize<<<NBUK, 256, 0, stream>>>(ebuf, bbase, rp, cols);
    wfuse<<<(IN_DIM * HID + 255) / 256, 256, 0, stream>>>(W_emb, W1, b_emb, W2,
                                                          Wt1, Wt2, bf);

    // --- layer 1: T1 = h @ Wf + bf (bf16, MFMA);  z1 = gather(T1) + b1 ---
    gemm_l1<<<blkT, 384, 0, stream>>>(h, Wt1, bf, T);
    gather_stats<<<NB_GATH, 192, 0, stream>>>(T, rp, cols, b1, z, psums, psq);
    bn_finalize<<<1, 384, 0, stream>>>(psums, psq, g1, be1, scale, shift);

    // --- layer 2: T2 = relu(bn1(z1)) @ W2 (bf16, MFMA);  z2 = gather + b2 ---
    gemm_l2<<<blkT, 384, 0, stream>>>(z, Wt2, scale, shift, T);
    gather_stats<<<NB_GATH, 192, 0, stream>>>(T, rp, cols, b2, z, psums, psq);
    bn_finalize<<<1, 384, 0, stream>>>(psums, psq, g2, be2, scale, shift);

    // --- readout (BN2+ReLU fused) + log_softmax ---
    readout_kernel<<<2048, 256, 0, stream>>>(z, scale, shift, Wr, br, (float*)d_out);
}